// Round 7
// baseline (160.278 us; speedup 1.0000x reference)
//
#include <hip/hip_runtime.h>

// Problem constants
#define BATCH   8
#define NNODES  16384
#define KNBR    16
#define LATENT  128
#define DOUT    32
#define NROWS   (BATCH * NNODES)          // 131072 rows

typedef __attribute__((ext_vector_type(8))) short short8;   // 8 bf16 (4 VGPRs)
typedef __attribute__((ext_vector_type(4))) float floatx4;  // native float4
typedef __attribute__((ext_vector_type(4))) unsigned uintx4;

__device__ __forceinline__ unsigned short f2bf(float f) {   // fp32 -> bf16 RNE
    unsigned u = __float_as_uint(f);
    u += 0x7fff + ((u >> 16) & 1);
    return (unsigned short)(u >> 16);
}

__device__ __forceinline__ short8 pack8(const floatx4 a, const floatx4 b) {
    short8 r;
    r[0] = (short)f2bf(a.x); r[1] = (short)f2bf(a.y);
    r[2] = (short)f2bf(a.z); r[3] = (short)f2bf(a.w);
    r[4] = (short)f2bf(b.x); r[5] = (short)f2bf(b.y);
    r[6] = (short)f2bf(b.z); r[7] = (short)f2bf(b.w);
    return r;
}

__device__ __forceinline__ float dot2bf(unsigned a, unsigned b) {
    float alo = __uint_as_float(a << 16);
    float ahi = __uint_as_float(a & 0xffff0000u);
    float blo = __uint_as_float(b << 16);
    float bhi = __uint_as_float(b & 0xffff0000u);
    return alo * blo + ahi * bhi;
}

// ---------------------------------------------------------------------------
// Kernel 1: bf16 MFMA projection, LDS-free.
// Block = 4 waves x 32 rows = 128 rows; C[128 x 64] = feats[128x128]*[kw|qw]^T.
// 32 rows/wave (rt=2 tiles of 16x16) -> 4096 waves = 16 waves/CU for latency
// hiding (64 rows/wave gave only 8/CU and left both pipes idle).
// A has zero cross-wave reuse -> fragments load straight from global
// (per wave-instr: 16 rows x 128B contiguous). B (32KB) is L1-resident.
// No __shared__, no __syncthreads.
// ---------------------------------------------------------------------------
__global__ __launch_bounds__(256) void proj_kernel(
    const float* __restrict__ feats,
    const float* __restrict__ kw, const float* __restrict__ kb,
    const float* __restrict__ qw, const float* __restrict__ qb,
    unsigned short* __restrict__ tkb, unsigned short* __restrict__ tqb)
{
    const int tid  = threadIdx.x;
    const int lane = tid & 63;
    const int w    = tid >> 6;                 // wave 0..3
    const long long blk_row = (long long)blockIdx.x * 128;
    const int m = lane & 15;                   // MFMA row (A) / col (B,C)
    const int q = lane >> 4;                   // quad: k-offset q*8

    floatx4 acc[2][4];
#pragma unroll
    for (int rt = 0; rt < 2; ++rt)
#pragma unroll
        for (int ct = 0; ct < 4; ++ct) acc[rt][ct] = (floatx4){0.f, 0.f, 0.f, 0.f};

    const floatx4* f4  = (const floatx4*)feats;  // feature row = 32 f4
    const floatx4* kw4 = (const floatx4*)kw;     // 32 rows x 32 f4
    const floatx4* qw4 = (const floatx4*)qw;

#pragma unroll
    for (int ks = 0; ks < 4; ++ks) {
        const int kf4 = ks * 8 + q * 2;        // first of 2 f4 cols this lane needs

        // B fragments: rows ct*16+m of [kw ; qw]
        short8 bf[4];
#pragma unroll
        for (int ct = 0; ct < 4; ++ct) {
            const floatx4* wb = (ct < 2) ? kw4 : qw4;
            const int row = (ct & 1) * 16 + m;
            const floatx4 b0 = wb[row * 32 + kf4];
            const floatx4 b1 = wb[row * 32 + kf4 + 1];
            bf[ct] = pack8(b0, b1);
        }
#pragma unroll
        for (int rt = 0; rt < 2; ++rt) {
            const long long arow = blk_row + w * 32 + rt * 16 + m;
            const floatx4 a0 = f4[arow * 32 + kf4];
            const floatx4 a1 = f4[arow * 32 + kf4 + 1];
            const short8 af = pack8(a0, a1);
#pragma unroll
            for (int ct = 0; ct < 4; ++ct)
                acc[rt][ct] = __builtin_amdgcn_mfma_f32_16x16x32_bf16(af, bf[ct], acc[rt][ct], 0, 0, 0);
        }
    }

    // Epilogue: bias + bf16 store. C/D layout: col = lane&15, row = q*4+reg.
    float bias[4];
#pragma unroll
    for (int ct = 0; ct < 4; ++ct)
        bias[ct] = (ct < 2) ? kb[ct * 16 + m] : qb[(ct - 2) * 16 + m];

#pragma unroll
    for (int rt = 0; rt < 2; ++rt) {
#pragma unroll
        for (int reg = 0; reg < 4; ++reg) {
            const long long row = blk_row + w * 32 + rt * 16 + q * 4 + reg;
#pragma unroll
            for (int ct = 0; ct < 4; ++ct) {
                const float val = acc[rt][ct][reg] + bias[ct];
                if (ct < 2) tkb[row * DOUT + ct * 16 + m]       = f2bf(val);
                else        tqb[row * DOUT + (ct - 2) * 16 + m] = f2bf(val);
            }
        }
    }
}

// ---------------------------------------------------------------------------
// Kernel 2: gather + scaled dot on bf16 tables, cooperative-4.
// 4 lanes read one 64B row (4 x uint4), dot in-lane, 2-step shfl reduce.
// blockIdx%8 == batch: each batch's 2MB (tk+tq bf16) fits one XCD's 4MB L2.
// idx loads / out stores are NONTEMPORAL so the streams don't evict tables.
// ---------------------------------------------------------------------------
__global__ __launch_bounds__(256) void gather_dot_kernel(
    const unsigned short* __restrict__ tkb, const unsigned short* __restrict__ tqb,
    const int* __restrict__ idx, float* __restrict__ out)
{
    const long long NK  = (long long)NNODES * KNBR;     // 262144 per batch
    const long long BNK = NK * BATCH;                   // 2097152 total

    const int b   = blockIdx.x & 7;
    const int blk = blockIdx.x >> 3;
    const int grp = threadIdx.x >> 2;   // 0..63: output within pass
    const int j   = threadIdx.x & 3;    // uint4 column within the 64B row

    const uintx4* tb_k = (const uintx4*)(tkb + (long long)b * NNODES * DOUT);
    const uintx4* tb_q = (const uintx4*)(tqb + (long long)b * NNODES * DOUT);

#pragma unroll
    for (int p = 0; p < 4; ++p) {
        const long long local = (long long)blk * 256 + p * 64 + grp;  // < NK
        const long long o     = (long long)b * NK + local;

        const int xi = __builtin_nontemporal_load(&idx[BNK + o]);        // channel 1
        const int yi = __builtin_nontemporal_load(&idx[2 * BNK + o]);    // channel 2

        const uintx4 x = tb_k[(long long)xi * 4 + j];
        const uintx4 y = tb_q[(long long)yi * 4 + j];
        float s = dot2bf(x.x, y.x) + dot2bf(x.y, y.y)
                + dot2bf(x.z, y.z) + dot2bf(x.w, y.w);
        s += __shfl_xor(s, 1);
        s += __shfl_xor(s, 2);
        if (j == 0)
            __builtin_nontemporal_store(s * 0.17677669529663687f, &out[o]);  // 32^-0.5
    }
}

// ---------------------------------------------------------------------------
extern "C" void kernel_launch(void* const* d_in, const int* in_sizes, int n_in,
                              void* d_out, int out_size, void* d_ws, size_t ws_size,
                              hipStream_t stream)
{
    const float* feats = (const float*)d_in[0];
    const float* kw    = (const float*)d_in[1];
    const float* kb    = (const float*)d_in[2];
    const float* qw    = (const float*)d_in[3];
    const float* qb    = (const float*)d_in[4];
    const int*   idx   = (const int*)d_in[5];
    float*       out   = (float*)d_out;

    // Workspace: two bf16 tables [B*N, 32] = 8 MB each
    unsigned short* tkb = (unsigned short*)d_ws;
    unsigned short* tqb = tkb + (long long)NROWS * DOUT;

    proj_kernel<<<NROWS / 128, 256, 0, stream>>>(feats, kw, kb, qw, qb, tkb, tqb);
    gather_dot_kernel<<<(int)((long long)BATCH * NNODES * KNBR / 256), 256, 0, stream>>>(
        tkb, tqb, idx, out);
}

// Round 8
// 152.619 us; speedup vs baseline: 1.0502x; 1.0502x over previous
//
#include <hip/hip_runtime.h>

// Problem constants
#define BATCH   8
#define NNODES  16384
#define KNBR    16
#define LATENT  128
#define DOUT    32
#define NROWS   (BATCH * NNODES)          // 131072 rows

typedef __attribute__((ext_vector_type(8))) short short8;   // 8 bf16 (4 VGPRs)
typedef __attribute__((ext_vector_type(4))) float floatx4;  // MFMA acc

__device__ __forceinline__ unsigned short f2bf(float f) {   // fp32 -> bf16 RNE
    unsigned u = __float_as_uint(f);
    u += 0x7fff + ((u >> 16) & 1);
    return (unsigned short)(u >> 16);
}

__device__ __forceinline__ float dot2bf(unsigned a, unsigned b) {
    // dot of two bf16 pairs packed in uints
    float alo = __uint_as_float(a << 16);
    float ahi = __uint_as_float(a & 0xffff0000u);
    float blo = __uint_as_float(b << 16);
    float bhi = __uint_as_float(b & 0xffff0000u);
    return alo * blo + ahi * bhi;
}

// ---------------------------------------------------------------------------
// Kernel 1: bf16 MFMA projection (R4 structure, 128-row blocks).
// C[128 x 64] per block = feats[128x128] * [kw|qw]^T.  4 waves; wave w owns
// rows [w*32, w*32+32) as 2x4 tiles of 16x16; K in 2 LDS chunks of 64.
// LDS = 18KB A + 17KB B -> 4 blocks/CU (vs 2 at 256 rows): barrier drains
// (4 syncs/block) are covered by other resident blocks (m114 overlap).
// Staging loads are 256B-dense per 16-lane group (the LDS-free variant's
// 32B-strided fragment loads measured 10us slower, R4 vs R6).
// ---------------------------------------------------------------------------
#define APAD 72     // A chunk row stride: 64 + 8 bf16 (144 B)
#define BPAD 136    // B row stride: 128 + 8 bf16 (272 B)

__global__ __launch_bounds__(256) void proj_kernel(
    const float* __restrict__ feats,
    const float* __restrict__ kw, const float* __restrict__ kb,
    const float* __restrict__ qw, const float* __restrict__ qb,
    unsigned short* __restrict__ tkb, unsigned short* __restrict__ tqb)
{
    __shared__ unsigned short A_lds[128 * APAD];   // 18 KB
    __shared__ unsigned short B_lds[64 * BPAD];    // 17 KB
    __shared__ float bias_lds[64];

    const int tid  = threadIdx.x;
    const int lane = tid & 63;
    const int w    = tid >> 6;                     // wave 0..3
    const long long blk_row = (long long)blockIdx.x * 128;

    // Stage B = [kw ; qw] as bf16: B_lds[col*BPAD + k] = W_cat[col][k]
    {
        const float4* kw4 = (const float4*)kw;     // [32 rows][32 f4]
        const float4* qw4 = (const float4*)qw;
#pragma unroll
        for (int i = 0; i < 8; ++i) {
            const int linear = i * 256 + tid;      // 0..2047
            const int row = linear >> 5;           // 0..63
            const int c4  = linear & 31;
            const float4 v = (row < 32) ? kw4[row * 32 + c4] : qw4[(row - 32) * 32 + c4];
            unsigned lo = f2bf(v.x) | ((unsigned)f2bf(v.y) << 16);
            unsigned hi = f2bf(v.z) | ((unsigned)f2bf(v.w) << 16);
            *(uint2*)&B_lds[row * BPAD + c4 * 4] = make_uint2(lo, hi);
        }
        if (tid < 64) bias_lds[tid] = (tid < 32) ? kb[tid] : qb[tid - 32];
    }

    const int m = lane & 15;   // MFMA row (A) / col (B,C)
    const int q = lane >> 4;   // quad

    floatx4 acc[2][4];
#pragma unroll
    for (int rt = 0; rt < 2; ++rt)
#pragma unroll
        for (int ct = 0; ct < 4; ++ct) acc[rt][ct] = (floatx4){0.f, 0.f, 0.f, 0.f};

    const float4* f4 = (const float4*)feats;       // feature row = 32 f4
    const int s_c4   = tid & 15;                   // staging f4 col within chunk
    const int s_rowg = tid >> 4;                   // staging row 0..15

    for (int ch = 0; ch < 2; ++ch) {
        __syncthreads();   // prev chunk consumed (ch0: orders B/bias writes too)
        // Stage A chunk: 128 rows x 64 floats (k in [ch*64, ch*64+64)) -> bf16
#pragma unroll
        for (int i = 0; i < 8; ++i) {
            const int row = i * 16 + s_rowg;
            const float4 v = f4[(blk_row + row) * 32 + ch * 16 + s_c4];
            unsigned lo = f2bf(v.x) | ((unsigned)f2bf(v.y) << 16);
            unsigned hi = f2bf(v.z) | ((unsigned)f2bf(v.w) << 16);
            *(uint2*)&A_lds[row * APAD + s_c4 * 4] = make_uint2(lo, hi);
        }
        __syncthreads();

#pragma unroll
        for (int ks = 0; ks < 2; ++ks) {
            const int kk = ks * 32 + q * 8;        // k within A chunk, this lane
            const int kg = ch * 64 + kk;           // global k for B
            short8 bf[4];
#pragma unroll
            for (int ct = 0; ct < 4; ++ct)
                bf[ct] = *(const short8*)&B_lds[(ct * 16 + m) * BPAD + kg];
#pragma unroll
            for (int rt = 0; rt < 2; ++rt) {
                const short8 af = *(const short8*)&A_lds[(w * 32 + rt * 16 + m) * APAD + kk];
#pragma unroll
                for (int ct = 0; ct < 4; ++ct)
                    acc[rt][ct] = __builtin_amdgcn_mfma_f32_16x16x32_bf16(af, bf[ct], acc[rt][ct], 0, 0, 0);
            }
        }
    }

    // Epilogue: bias + bf16 store. C/D layout: col = lane&15, row = q*4+reg.
#pragma unroll
    for (int rt = 0; rt < 2; ++rt) {
#pragma unroll
        for (int reg = 0; reg < 4; ++reg) {
            const long long row = blk_row + w * 32 + rt * 16 + q * 4 + reg;
#pragma unroll
            for (int ct = 0; ct < 4; ++ct) {
                const float val = acc[rt][ct][reg] + bias_lds[ct * 16 + m];
                if (ct < 2) tkb[row * DOUT + ct * 16 + m]       = f2bf(val);
                else        tqb[row * DOUT + (ct - 2) * 16 + m] = f2bf(val);
            }
        }
    }
}

// ---------------------------------------------------------------------------
// Kernel 2: gather + scaled dot on bf16 tables, cooperative-4 (R4 verbatim —
// the NT-hint variant measured +10us total; reverted).
// 4 lanes read one 64B row (4 x uint4), dot in-lane, 2-step shfl reduce.
// blockIdx%8 == batch: each batch's 2MB of tables fits one XCD's 4MB L2.
// ---------------------------------------------------------------------------
__global__ __launch_bounds__(256) void gather_dot_kernel(
    const unsigned short* __restrict__ tkb, const unsigned short* __restrict__ tqb,
    const int* __restrict__ idx, float* __restrict__ out)
{
    const long long NK  = (long long)NNODES * KNBR;     // 262144 per batch
    const long long BNK = NK * BATCH;                   // 2097152 total

    const int b   = blockIdx.x & 7;
    const int blk = blockIdx.x >> 3;
    const int grp = threadIdx.x >> 2;   // 0..63: output within pass
    const int j   = threadIdx.x & 3;    // uint4 column within the 64B row

    const uint4* tb_k = (const uint4*)(tkb + (long long)b * NNODES * DOUT);
    const uint4* tb_q = (const uint4*)(tqb + (long long)b * NNODES * DOUT);

#pragma unroll
    for (int p = 0; p < 4; ++p) {
        const long long local = (long long)blk * 256 + p * 64 + grp;  // < NK
        const long long o     = (long long)b * NK + local;

        const int xi = idx[BNK + o];        // channel 1
        const int yi = idx[2 * BNK + o];    // channel 2

        const uint4 x = tb_k[(long long)xi * 4 + j];
        const uint4 y = tb_q[(long long)yi * 4 + j];
        float s = dot2bf(x.x, y.x) + dot2bf(x.y, y.y)
                + dot2bf(x.z, y.z) + dot2bf(x.w, y.w);
        s += __shfl_xor(s, 1);
        s += __shfl_xor(s, 2);
        if (j == 0) out[o] = s * 0.17677669529663687f;   // 32^-0.5
    }
}

// ---------------------------------------------------------------------------
extern "C" void kernel_launch(void* const* d_in, const int* in_sizes, int n_in,
                              void* d_out, int out_size, void* d_ws, size_t ws_size,
                              hipStream_t stream)
{
    const float* feats = (const float*)d_in[0];
    const float* kw    = (const float*)d_in[1];
    const float* kb    = (const float*)d_in[2];
    const float* qw    = (const float*)d_in[3];
    const float* qb    = (const float*)d_in[4];
    const int*   idx   = (const int*)d_in[5];
    float*       out   = (float*)d_out;

    // Workspace: two bf16 tables [B*N, 32] = 8 MB each
    unsigned short* tkb = (unsigned short*)d_ws;
    unsigned short* tqb = tkb + (long long)NROWS * DOUT;

    proj_kernel<<<NROWS / 128, 256, 0, stream>>>(feats, kw, kb, qw, qb, tkb, tqb);
    gather_dot_kernel<<<(int)((long long)BATCH * NNODES * KNBR / 256), 256, 0, stream>>>(
        tkb, tqb, idx, out);
}